// Round 3
// baseline (9.932 us; speedup 1.0000x reference)
//
#include <hip/hip_runtime.h>

// output[b,f] = max_t ( x[b,t,f]==1 ? T-1-t : 0 )  ==  T-1-t_first  (first spike)
// Early-exit scan from t=0. CHUNK=32: P(neuron silent for 32 steps) = 2^-32,
// so every wave finishes in ONE dependent memory round with near certainty.
// Branchless: iterate k high->low with select-overwrite, so the last write wins
// = earliest timestep. Deterministic for fixed input.

__global__ __launch_bounds__(64) void first_spike_kernel(const float* __restrict__ x,
                                                         float* __restrict__ out,
                                                         int T, int F, int blocks_per_b) {
    const int b  = blockIdx.x / blocks_per_b;
    const int fb = blockIdx.x % blocks_per_b;
    const int f0 = (fb * 64 + threadIdx.x) * 4;   // 4 consecutive features per thread

    const float4* p = reinterpret_cast<const float4*>(
        x + (size_t)b * T * F + f0);
    const int strideVec = F / 4;   // float4 elements per timestep row

    float o0 = 0.f, o1 = 0.f, o2 = 0.f, o3 = 0.f;
    bool  d0 = false, d1 = false, d2 = false, d3 = false;

    constexpr int CHUNK = 32;      // 2048 % 32 == 0
    for (int t0 = 0; t0 < T; t0 += CHUNK) {
        // one round of independent loads (issued back-to-back, single waitcnt)
        float4 v[CHUNK];
#pragma unroll
        for (int k = 0; k < CHUNK; ++k)
            v[k] = p[(size_t)(t0 + k) * strideVec];

        // branchless: reverse order, select-overwrite -> earliest spike wins
#pragma unroll
        for (int k = CHUNK - 1; k >= 0; --k) {
            const float tv = (float)(T - 1 - (t0 + k));
            o0 = (v[k].x == 1.0f) ? tv : o0;
            o1 = (v[k].y == 1.0f) ? tv : o1;
            o2 = (v[k].z == 1.0f) ? tv : o2;
            o3 = (v[k].w == 1.0f) ? tv : o3;
            d0 |= (v[k].x == 1.0f);
            d1 |= (v[k].y == 1.0f);
            d2 |= (v[k].z == 1.0f);
            d3 |= (v[k].w == 1.0f);
        }
        if (d0 & d1 & d2 & d3) break;   // wave exits when all lanes done
    }

    float4* o = reinterpret_cast<float4*>(out + (size_t)b * F + f0);
    *o = make_float4(o0, o1, o2, o3);
}

extern "C" void kernel_launch(void* const* d_in, const int* in_sizes, int n_in,
                              void* d_out, int out_size, void* d_ws, size_t ws_size,
                              hipStream_t stream) {
    const float* x  = (const float*)d_in[0];
    float*       out = (float*)d_out;

    const int T = 2048;
    const int F = 1024;
    const int B = in_sizes[0] / (T * F);   // 64

    const int blocks_per_b = F / (64 * 4); // 4 blocks of 64 threads cover F=1024
    dim3 grid(B * blocks_per_b);           // 256 blocks -> one wave per CU
    dim3 block(64);

    hipLaunchKernelGGL(first_spike_kernel, grid, block, 0, stream,
                       x, out, T, F, blocks_per_b);
}